// Round 1
// 452.954 us; speedup vs baseline: 1.1562x; 1.1562x over previous
//
#include <hip/hip_runtime.h>

// Problem constants (from reference setup_inputs)
static constexpr int B = 4, C = 3, H = 1080, W = 1920;
static constexpr int HW = H * W;          // 2,073,600
static constexpr int NPIX = B * HW;       // 8,294,400
static constexpr int BLOCK = 256;

// Target-domain tiling. Tile 32x32 -> k_tile LDS = 4 KB (dmax) + 16 KB (acc)
// = 20 KB -> 8 WG/CU (exactly 160 KiB), 32 waves/CU (100% occupancy target).
static constexpr int TW = 32, TH = 32;
static constexpr int TPX = TW * TH;              // 1024
static constexpr int TXN = W / TW;               // 60 (exact)
static constexpr int TYN = (H + TH - 1) / TH;    // 34 (last tile 24 rows)
static constexpr int NT = TXN * TYN;             // 2040 tiles per batch
static constexpr int CAP = 1536;                 // entries/bin; mean ~1085, sigma ~33
static constexpr int OFL_CAP = 65536;            // overflow list capacity
static constexpr int BPB = HW / BLOCK;           // 8100 blocks per batch (exact)

// Depth key must match numpy bit-exactly: no FMA contraction, round-half-even.
__device__ __forceinline__ int depth_key(float fx, float fy) {
    float m2 = __fadd_rn(__fmul_rn(fx, fx), __fmul_rn(fy, fy));
    return (int)rintf(__fmul_rn(sqrtf(m2), 1000.0f));
}

// ---------------------------------------------------------------------------
// Pass 1: bin every source pixel into the tile(s) its 2x2 corner footprint
// touches (~1.06 avg), via a per-block LDS histogram (one global atomic per
// unique tile per block). Entries are now FAT: {x, y, pix, d} (16 B), so
// k_tile never re-gathers flow nor recomputes the div/sqrt chain — its
// per-entry critical path becomes a single coalesced float4 load.
__global__ __launch_bounds__(BLOCK) void k_bin(const float2* __restrict__ flow,
                                               int* __restrict__ cnt,
                                               float4* __restrict__ bin,
                                               int* __restrict__ ofl_cnt,
                                               int* __restrict__ ofl_i,
                                               int* __restrict__ ofl_t,
                                               int* __restrict__ dbuf) {
    __shared__ int hcnt[NT];    // 8160 B: per-block per-tile count
    __shared__ int hbase[NT];   // 8160 B: global base slot for this block
    const int tid = threadIdx.x;

    // Issue the flow load BEFORE the LDS init loop so its latency hides.
    const int b = blockIdx.x / BPB;               // all threads in block share b
    const int i = blockIdx.x * BLOCK + tid;
    const float2 f = flow[i];

    for (int j = tid; j < NT; j += BLOCK) hcnt[j] = 0;
    __syncthreads();

    const int pix = i - b * HW;
    const int h = pix / W;
    const int w = pix - h * W;
    const float x = (float)w + f.x;
    const float y = (float)h + f.y;
    const int x0 = (int)floorf(x);
    const int y0 = (int)floorf(y);
    const int d = depth_key(f.x, f.y);

    // Phase 1: dedup'd tile list + rank within block (LDS atomics).
    int tl[4], rk[4]; int ntl = 0;
    #pragma unroll
    for (int dy = 0; dy < 2; ++dy) {
        int cy = y0 + dy;
        if ((unsigned)cy >= (unsigned)H) continue;
        #pragma unroll
        for (int dx = 0; dx < 2; ++dx) {
            int cx = x0 + dx;
            if ((unsigned)cx >= (unsigned)W) continue;
            int t = (cy >> 5) * TXN + (cx >> 5);
            bool dup = false;
            for (int k = 0; k < ntl; ++k) dup |= (tl[k] == t);
            if (dup) continue;
            tl[ntl] = t;
            rk[ntl] = atomicAdd(&hcnt[t], 1);
            ++ntl;
        }
    }
    __syncthreads();

    // Phase 2: one global atomic per touched tile, grab base slots.
    for (int j = tid; j < NT; j += BLOCK) {
        int c = hcnt[j];
        if (c > 0) hbase[j] = atomicAdd(&cnt[b * NT + j], c);
    }
    __syncthreads();

    // Phase 3: write fat entries at base+rank (consecutive slots per tile per
    // block -> clustered 16B stores). Overflow (never expected): depth merged
    // directly into global dbuf, accumulation deferred to the overflow list.
    const float4 entry = make_float4(x, y, __int_as_float(pix), __int_as_float(d));
    bool did_depth_fb = false;
    for (int k = 0; k < ntl; ++k) {
        int t = tl[k];
        int slot = hbase[t] + rk[k];
        if (slot < CAP) {
            bin[(size_t)(b * NT + t) * CAP + slot] = entry;
        } else {
            int pos = atomicAdd(ofl_cnt, 1);
            if (pos < OFL_CAP) { ofl_i[pos] = i; ofl_t[pos] = t; }
            if (!did_depth_fb) {
                did_depth_fb = true;   // corners repeat across tiles; merge once
                #pragma unroll
                for (int yy = 0; yy < 2; ++yy) {
                    int cy2 = y0 + yy;
                    if ((unsigned)cy2 >= (unsigned)H) continue;
                    #pragma unroll
                    for (int xx = 0; xx < 2; ++xx) {
                        int cx2 = x0 + xx;
                        if ((unsigned)cx2 >= (unsigned)W) continue;
                        atomicMax(&dbuf[b * HW + cy2 * W + cx2], d);
                    }
                }
            }
        }
    }
}

// ---------------------------------------------------------------------------
// Pass 2: fused depth+accumulate per tile, driven by the fat bin. In the
// common no-overflow case dbuf is neither read nor published (saves 66 MB),
// and the normalized output is written directly.
__global__ __launch_bounds__(BLOCK, 8) void k_tile(const float* __restrict__ im0,
                                                   const int* __restrict__ cnt,
                                                   const float4* __restrict__ bin,
                                                   const int* __restrict__ ofl_cnt,
                                                   int* __restrict__ dbuf,
                                                   float* __restrict__ wght,
                                                   float* __restrict__ out) {
    __shared__ int    dmax[TPX];      // 4 KB
    __shared__ float4 accv[TPX];      // 16 KB, interleaved (w,c0,c1,c2): one
                                      // thread's 4 atomics hit 4 distinct banks
    float* accf = (float*)accv;
    const int tid = threadIdx.x;
    const int bx = blockIdx.x, by = blockIdx.y, b = blockIdx.z;
    const int tx0 = bx * TW, ty0 = by * TH;
    const int t = by * TXN + bx;
    const bool have_ofl = (*ofl_cnt) > 0;   // uniform, input-determined
    int* db = dbuf + (size_t)b * HW;

    for (int i = tid; i < TPX; i += BLOCK) {
        int gy = ty0 + (i >> 5), gx = tx0 + (i & 31);
        dmax[i] = (have_ofl && gy < H) ? db[gy * W + gx] : 0;
        accv[i] = make_float4(0.0f, 0.0f, 0.0f, 0.0f);
    }
    __syncthreads();

    const int n = min(cnt[b * NT + t], CAP);
    const float4* mybin = bin + (size_t)(b * NT + t) * CAP;

    // scan 1: depth max into LDS. Per entry: one coalesced 16B load + floor +
    // LDS atomicMax. No flow gather, no div, no sqrt.
    for (int e = tid; e < n; e += BLOCK) {
        float4 en = mybin[e];
        int x0 = (int)floorf(en.x);
        int y0 = (int)floorf(en.y);
        int d = __float_as_int(en.w);
        #pragma unroll
        for (int dy = 0; dy < 2; ++dy) {
            int cy = y0 + dy;
            if ((cy >> 5) != by || cy >= H) continue;
            #pragma unroll
            for (int dx = 0; dx < 2; ++dx) {
                int cx = x0 + dx;
                if ((cx >> 5) != bx) continue;
                atomicMax(&dmax[((cy - ty0) << 5) + (cx - tx0)], d);
            }
        }
    }
    __syncthreads();

    // publish merged depth only when the overflow kernel will need it
    if (have_ofl) {
        for (int i = tid; i < TPX; i += BLOCK) {
            int gy = ty0 + (i >> 5), gx = tx0 + (i & 31);
            if (gy < H) db[gy * W + gx] = dmax[i];
        }
    }

    // scan 2: depth-tested accumulation (bin slice is L1/L2-hot, 17 KB/tile;
    // dmax read-only from here -> no race with the publish loop)
    const float* ib = im0 + (size_t)b * C * HW;
    for (int e = tid; e < n; e += BLOCK) {
        float4 en = mybin[e];
        float x0f = floorf(en.x), y0f = floorf(en.y);
        int x0 = (int)x0f, y0 = (int)y0f;
        float ax = __fsub_rn(en.x, x0f);
        float ay = __fsub_rn(en.y, y0f);
        int pix = __float_as_int(en.z);
        int d   = __float_as_int(en.w);
        float wxv[2] = { __fsub_rn(1.0f, ax), ax };
        float wyv[2] = { __fsub_rn(1.0f, ay), ay };
        int   locs[4]; float lw[4]; int nw = 0;
        #pragma unroll
        for (int dy = 0; dy < 2; ++dy) {
            int cy = y0 + dy;
            if ((cy >> 5) != by || cy >= H) continue;
            #pragma unroll
            for (int dx = 0; dx < 2; ++dx) {
                int cx = x0 + dx;
                if ((cx >> 5) != bx) continue;
                int loc = ((cy - ty0) << 5) + (cx - tx0);
                if (dmax[loc] != d) continue;
                locs[nw] = loc;
                lw[nw] = __fmul_rn(wxv[dx], wyv[dy]);
                ++nw;
            }
        }
        if (nw) {
            float c0 = ib[pix];
            float c1 = ib[pix + HW];
            float c2 = ib[pix + 2 * HW];
            for (int k = 0; k < nw; ++k) {
                int p = locs[k]; float wg = lw[k];
                atomicAdd(&accf[4 * p + 0], wg);
                atomicAdd(&accf[4 * p + 1], __fmul_rn(c0, wg));
                atomicAdd(&accf[4 * p + 2], __fmul_rn(c1, wg));
                atomicAdd(&accf[4 * p + 3], __fmul_rn(c2, wg));
            }
        }
    }
    __syncthreads();

    float* ob = out + (size_t)b * C * HW;
    float* wb = wght + (size_t)b * HW;
    for (int i = tid; i < TPX; i += BLOCK) {
        int gy = ty0 + (i >> 5), gx = tx0 + (i & 31);
        if (gy >= H) continue;
        int g = gy * W + gx;
        float4 a = accv[i];   // ds_read_b128
        if (have_ofl) {  // overflow exists: store raw sums, norm pass finishes
            wb[g] = a.x;
            ob[g] = a.y; ob[g + HW] = a.z; ob[g + 2 * HW] = a.w;
        } else {         // common case: fused normalize
            float wv = fmaxf(a.x, 1e-5f);
            ob[g]          = __fdiv_rn(a.y, wv);
            ob[g + HW]     = __fdiv_rn(a.z, wv);
            ob[g + 2 * HW] = __fdiv_rn(a.w, wv);
        }
    }
}

// ---------------------------------------------------------------------------
// Overflow accumulation (normally zero work): global atomics, corners
// restricted to the overflowed tile (other tiles own their own copies).
__global__ __launch_bounds__(BLOCK) void k_accum_ofl(const float* __restrict__ im0,
                                                     const float2* __restrict__ flow,
                                                     const int* __restrict__ ofl_cnt,
                                                     const int* __restrict__ ofl_i,
                                                     const int* __restrict__ ofl_t,
                                                     const int* __restrict__ dbuf,
                                                     float* __restrict__ wght,
                                                     float* __restrict__ out) {
    int k = blockIdx.x * BLOCK + threadIdx.x;
    int n = min(*ofl_cnt, OFL_CAP);
    if (k >= n) return;
    int i = ofl_i[k], t = ofl_t[k];
    int b = i / HW;
    int pix = i - b * HW;
    int h = pix / W, w = pix - h * W;
    int bx = t % TXN, by = t / TXN;
    float2 f = flow[i];
    float x = (float)w + f.x;
    float y = (float)h + f.y;
    float x0f = floorf(x), y0f = floorf(y);
    int x0 = (int)x0f, y0 = (int)y0f;
    float ax = __fsub_rn(x, x0f);
    float ay = __fsub_rn(y, y0f);
    int d = depth_key(f.x, f.y);
    const float* src = im0 + (size_t)b * C * HW + pix;
    float c0 = src[0], c1 = src[HW], c2 = src[2 * HW];
    float wxv[2] = { __fsub_rn(1.0f, ax), ax };
    float wyv[2] = { __fsub_rn(1.0f, ay), ay };
    #pragma unroll
    for (int dy = 0; dy < 2; ++dy) {
        int cy = y0 + dy;
        if ((cy >> 5) != by || cy >= H) continue;
        #pragma unroll
        for (int dx = 0; dx < 2; ++dx) {
            int cx = x0 + dx;
            if ((cx >> 5) != bx) continue;
            int idx = b * HW + cy * W + cx;
            if (dbuf[idx] != d) continue;
            float wg = __fmul_rn(wxv[dx], wyv[dy]);
            atomicAdd(&wght[idx], wg);
            float* o = out + (size_t)b * C * HW + cy * W + cx;
            atomicAdd(&o[0],      __fmul_rn(c0, wg));
            atomicAdd(&o[HW],     __fmul_rn(c1, wg));
            atomicAdd(&o[2 * HW], __fmul_rn(c2, wg));
        }
    }
}

// Norm pass: only active when overflow occurred (k_tile stored raw sums).
// Grid-stride so the no-overflow early-exit costs ~nothing.
__global__ __launch_bounds__(BLOCK) void k_norm(float* __restrict__ out,
                                                const float* __restrict__ wght,
                                                const int* __restrict__ ofl_cnt) {
    if (*ofl_cnt == 0) return;
    for (int i = blockIdx.x * BLOCK + threadIdx.x; i < NPIX;
         i += gridDim.x * BLOCK) {
        int b = i / HW;
        int pix = i - b * HW;
        float wv = fmaxf(wght[i], 1e-5f);
        float* o = out + (size_t)b * C * HW + pix;
        o[0]      = __fdiv_rn(o[0], wv);
        o[HW]     = __fdiv_rn(o[HW], wv);
        o[2 * HW] = __fdiv_rn(o[2 * HW], wv);
    }
}

extern "C" void kernel_launch(void* const* d_in, const int* in_sizes, int n_in,
                              void* d_out, int out_size, void* d_ws, size_t ws_size,
                              hipStream_t stream) {
    const float*  im0  = (const float*)d_in[0];   // [B,C,H,W]
    const float2* flow = (const float2*)d_in[1];  // [B,H,W,2] as float2
    float* out = (float*)d_out;                   // [B,C,H,W]

    // Workspace layout (bytes): bin first (16B-aligned), then scalars.
    char* ws = (char*)d_ws;
    float4* bin = (float4*)ws;                                      // B*NT*CAP*16 (~200 MB)
    const size_t bin_bytes = (size_t)B * NT * CAP * sizeof(float4);
    int*   dbuf    = (int*)(ws + bin_bytes);                        // NPIX
    float* wght    = (float*)(ws + bin_bytes + (size_t)NPIX * 4);   // NPIX
    int*   cnt     = (int*)(ws + bin_bytes + (size_t)NPIX * 8);     // B*NT
    int*   ofl_cnt = cnt + B * NT;                                  // 1 (adjacent to cnt)
    int*   ofl_i   = ofl_cnt + 1;                                   // OFL_CAP
    int*   ofl_t   = ofl_i + OFL_CAP;                               // OFL_CAP

    hipMemsetAsync(dbuf, 0, (size_t)NPIX * 4, stream);
    hipMemsetAsync(cnt, 0, (size_t)(B * NT + 1) * 4, stream);

    int lgrid = NPIX / BLOCK;   // exact: 32400
    dim3 tgrid(TXN, TYN, B);    // 60 x 34 x 4 = 8160 tiles

    k_bin      <<<lgrid, BLOCK, 0, stream>>>(flow, cnt, bin, ofl_cnt, ofl_i, ofl_t, dbuf);
    k_tile     <<<tgrid, BLOCK, 0, stream>>>(im0, cnt, bin, ofl_cnt, dbuf, wght, out);
    k_accum_ofl<<<OFL_CAP / BLOCK, BLOCK, 0, stream>>>(im0, flow, ofl_cnt, ofl_i, ofl_t, dbuf, wght, out);
    k_norm     <<<2048, BLOCK, 0, stream>>>(out, wght, ofl_cnt);
}

// Round 2
// 428.430 us; speedup vs baseline: 1.2224x; 1.0572x over previous
//
#include <hip/hip_runtime.h>

// Problem constants (from reference setup_inputs)
static constexpr int B = 4, C = 3, H = 1080, W = 1920;
static constexpr int HW = H * W;          // 2,073,600
static constexpr int NPIX = B * HW;       // 8,294,400
static constexpr int BLOCK = 256;

// Target-domain tiling. Tile 32x32 -> k_tile LDS = 4 KB (dmax) + 16 KB (acc)
// = 20 KB -> 8 WG/CU by LDS.
static constexpr int TW = 32, TH = 32;
static constexpr int TPX = TW * TH;              // 1024
static constexpr int TXN = W / TW;               // 60 (exact)
static constexpr int TYN = (H + TH - 1) / TH;    // 34 (last tile 24 rows)
static constexpr int NT = TXN * TYN;             // 2040 tiles per batch
static constexpr int CAP = 1536;                 // entries/bin; mean ~1085, sigma ~33
static constexpr int EPT = CAP / BLOCK;          // 6 entries/thread max (exact)
static constexpr int OFL_CAP = 65536;            // overflow list capacity

// k_bin: 4 pixels per thread -> 8100 blocks; histogram amortized 4x.
static constexpr int PPT = 4;
static constexpr int BPIX = BLOCK * PPT;         // 1024 pixels per block
static constexpr int BPB = HW / BPIX;            // 2025 blocks per batch (exact)

// Depth key must match numpy bit-exactly: no FMA contraction, round-half-even.
__device__ __forceinline__ int depth_key(float fx, float fy) {
    float m2 = __fadd_rn(__fmul_rn(fx, fx), __fmul_rn(fy, fy));
    return (int)rintf(__fmul_rn(sqrtf(m2), 1000.0f));
}

// Overflow-path fallback: merge this pixel's full footprint into global dbuf.
__device__ __forceinline__ void merge_depth(int* __restrict__ dbuf, int bHW,
                                            float x, float y, int d) {
    int x0 = (int)floorf(x), y0 = (int)floorf(y);
    #pragma unroll
    for (int yy = 0; yy < 2; ++yy) {
        int cy = y0 + yy;
        if ((unsigned)cy >= (unsigned)H) continue;
        #pragma unroll
        for (int xx = 0; xx < 2; ++xx) {
            int cx = x0 + xx;
            if ((unsigned)cx >= (unsigned)W) continue;
            atomicMax(&dbuf[bHW + cy * W + cx], d);
        }
    }
}

// ---------------------------------------------------------------------------
// Pass 1: bin every source pixel into the tile(s) its 2x2 corner footprint
// touches (~1.06 avg). Per-block LDS histogram -> one global atomic per
// unique tile per block. 4 px/thread amortizes the NT-sized init/sweep loops
// and clusters phase-3 writes. Dedup is fully static (no runtime-indexed
// arrays -> no scratch).
__global__ __launch_bounds__(BLOCK) void k_bin(const float2* __restrict__ flow,
                                               int* __restrict__ cnt,
                                               float4* __restrict__ bin,
                                               int* __restrict__ ofl_cnt,
                                               int* __restrict__ ofl_i,
                                               int* __restrict__ ofl_t,
                                               int* __restrict__ dbuf) {
    __shared__ int hcnt[NT];    // per-block per-tile count
    __shared__ int hbase[NT];   // global base slot for this block
    const int tid = threadIdx.x;
    const int b = blockIdx.x / BPB;              // block never straddles batches
    const int gbase = blockIdx.x * BPIX + tid;

    // Issue all flow loads BEFORE the LDS init loop so their latency hides.
    float2 f[PPT];
    #pragma unroll
    for (int k = 0; k < PPT; ++k) f[k] = flow[gbase + k * BLOCK];

    for (int j = tid; j < NT; j += BLOCK) hcnt[j] = 0;
    __syncthreads();

    // Phase 1: static dedup'd tile ids (-1 = absent) + rank via LDS atomics.
    float xs[PPT], ys[PPT];
    int dd[PPT];
    int ta[PPT], tb[PPT], tc[PPT], td[PPT];
    int ra[PPT], rb[PPT], rc[PPT], rd[PPT];
    #pragma unroll
    for (int k = 0; k < PPT; ++k) {
        const int i = gbase + k * BLOCK;
        const int pix = i - b * HW;
        const int h = pix / W;
        const int w = pix - h * W;
        const float x = (float)w + f[k].x;
        const float y = (float)h + f[k].y;
        xs[k] = x; ys[k] = y;
        dd[k] = depth_key(f[k].x, f[k].y);
        const int x0 = (int)floorf(x), y0 = (int)floorf(y);
        const int x1 = x0 + 1, y1 = y0 + 1;
        const bool vx0 = (unsigned)x0 < (unsigned)W, vx1 = (unsigned)x1 < (unsigned)W;
        const bool vy0 = (unsigned)y0 < (unsigned)H, vy1 = (unsigned)y1 < (unsigned)H;
        const int cx0 = x0 >> 5, cx1 = x1 >> 5;
        const int cy0 = y0 >> 5, cy1 = y1 >> 5;
        const bool dupx = (cx1 == cx0), dupy = (cy1 == cy0);
        // (dupx && !vx0 && vx1) is impossible: same tile => same validity.
        ta[k] = (vy0 && vx0)                   ? cy0 * TXN + cx0 : -1;
        tb[k] = (vy0 && vx1 && !dupx)          ? cy0 * TXN + cx1 : -1;
        tc[k] = (vy1 && vx0 && !dupy)          ? cy1 * TXN + cx0 : -1;
        td[k] = (vy1 && vx1 && !dupx && !dupy) ? cy1 * TXN + cx1 : -1;
        ra[k] = (ta[k] >= 0) ? atomicAdd(&hcnt[ta[k]], 1) : 0;
        rb[k] = (tb[k] >= 0) ? atomicAdd(&hcnt[tb[k]], 1) : 0;
        rc[k] = (tc[k] >= 0) ? atomicAdd(&hcnt[tc[k]], 1) : 0;
        rd[k] = (td[k] >= 0) ? atomicAdd(&hcnt[td[k]], 1) : 0;
    }
    __syncthreads();

    // Phase 2: one global atomic per touched tile, grab base slots.
    for (int j = tid; j < NT; j += BLOCK) {
        int c = hcnt[j];
        if (c > 0) hbase[j] = atomicAdd(&cnt[b * NT + j], c);
    }
    __syncthreads();

    // Phase 3: write fat entries {x,y,pix,d} at base+rank (clustered stores).
    // Overflow (never expected): depth merged into global dbuf once per
    // pixel, accumulation deferred to the overflow list.
    #pragma unroll
    for (int k = 0; k < PPT; ++k) {
        const int i = gbase + k * BLOCK;
        const int pix = i - b * HW;
        const float4 entry = make_float4(xs[k], ys[k],
                                         __int_as_float(pix), __int_as_float(dd[k]));
        bool fb = false;
        #define EMIT(T, R)                                                     \
            if ((T) >= 0) {                                                    \
                int slot = hbase[T] + (R);                                     \
                if (slot < CAP) {                                              \
                    bin[(size_t)(b * NT + (T)) * CAP + slot] = entry;          \
                } else {                                                       \
                    int pos = atomicAdd(ofl_cnt, 1);                           \
                    if (pos < OFL_CAP) { ofl_i[pos] = i; ofl_t[pos] = (T); }   \
                    if (!fb) {                                                 \
                        fb = true;                                             \
                        merge_depth(dbuf, b * HW, xs[k], ys[k], dd[k]);        \
                    }                                                          \
                }                                                              \
            }
        EMIT(ta[k], ra[k])
        EMIT(tb[k], rb[k])
        EMIT(tc[k], rc[k])
        EMIT(td[k], rd[k])
        #undef EMIT
    }
}

// ---------------------------------------------------------------------------
// Pass 2: fused depth+accumulate per tile. The whole bin slice is held in
// REGISTERS (n <= CAP = 6*BLOCK): one clustered batch of 6 independent loads
// per thread, then scan1 (depth max) and scan2 (accumulate) run load-free
// except the im0 color gather, which is issued in a separate mask phase so
// all gathers are in flight before any consumer.
__global__ __launch_bounds__(BLOCK) void k_tile(const float* __restrict__ im0,
                                                const int* __restrict__ cnt,
                                                const float4* __restrict__ bin,
                                                const int* __restrict__ ofl_cnt,
                                                int* __restrict__ dbuf,
                                                float* __restrict__ wght,
                                                float* __restrict__ out) {
    __shared__ int    dmax[TPX];      // 4 KB
    __shared__ float4 accv[TPX];      // 16 KB interleaved (w,c0,c1,c2)
    float* accf = (float*)accv;
    const int tid = threadIdx.x;
    const int bx = blockIdx.x, by = blockIdx.y, b = blockIdx.z;
    const int tx0 = bx * TW, ty0 = by * TH;
    const int t = by * TXN + bx;
    const bool have_ofl = (*ofl_cnt) > 0;   // uniform, input-determined
    int* db = dbuf + (size_t)b * HW;

    const int n = min(cnt[b * NT + t], CAP);
    const float4* mybin = bin + (size_t)(b * NT + t) * CAP;

    // Clustered load of this thread's <=6 entries (clamped index -> no
    // branches between the loads; all 6 misses overlap).
    const int emax = max(n - 1, 0);
    float4 eA[EPT];
    #pragma unroll
    for (int k = 0; k < EPT; ++k) {
        int e = min(tid + k * BLOCK, emax);
        eA[k] = mybin[e];
    }

    for (int i = tid; i < TPX; i += BLOCK) {
        int gy = ty0 + (i >> 5), gx = tx0 + (i & 31);
        dmax[i] = (have_ofl && gy < H) ? db[gy * W + gx] : 0;
        accv[i] = make_float4(0.0f, 0.0f, 0.0f, 0.0f);
    }
    __syncthreads();

    // scan 1: depth max into LDS, straight from registers.
    #pragma unroll
    for (int k = 0; k < EPT; ++k) {
        if (tid + k * BLOCK < n) {
            float4 en = eA[k];
            int x0 = (int)floorf(en.x);
            int y0 = (int)floorf(en.y);
            int d = __float_as_int(en.w);
            #pragma unroll
            for (int dy = 0; dy < 2; ++dy) {
                int cy = y0 + dy;
                if ((cy >> 5) != by || cy >= H) continue;
                #pragma unroll
                for (int dx = 0; dx < 2; ++dx) {
                    int cx = x0 + dx;
                    if ((cx >> 5) != bx) continue;
                    atomicMax(&dmax[((cy - ty0) << 5) + (cx - tx0)], d);
                }
            }
        }
    }
    __syncthreads();

    // publish merged depth only when the overflow kernel will need it
    if (have_ofl) {
        for (int i = tid; i < TPX; i += BLOCK) {
            int gy = ty0 + (i >> 5), gx = tx0 + (i & 31);
            if (gy < H) db[gy * W + gx] = dmax[i];
        }
    }

    // scan 2, phase A: winner masks + issue ALL im0 gathers.
    const float* ib = im0 + (size_t)b * C * HW;
    int   wmask[EPT];
    float c0[EPT], c1[EPT], c2[EPT];
    #pragma unroll
    for (int k = 0; k < EPT; ++k) {
        wmask[k] = 0;
        if (tid + k * BLOCK < n) {
            float4 en = eA[k];
            int x0 = (int)floorf(en.x);
            int y0 = (int)floorf(en.y);
            int d = __float_as_int(en.w);
            int m = 0;
            #pragma unroll
            for (int dy = 0; dy < 2; ++dy) {
                int cy = y0 + dy;
                if ((cy >> 5) != by || cy >= H) continue;
                #pragma unroll
                for (int dx = 0; dx < 2; ++dx) {
                    int cx = x0 + dx;
                    if ((cx >> 5) != bx) continue;
                    if (dmax[((cy - ty0) << 5) + (cx - tx0)] == d)
                        m |= 1 << (dy * 2 + dx);
                }
            }
            wmask[k] = m;
            if (m) {
                int pix = __float_as_int(en.z);
                c0[k] = ib[pix];
                c1[k] = ib[pix + HW];
                c2[k] = ib[pix + 2 * HW];
            }
        }
    }

    // scan 2, phase B: accumulate winners (weights recomputed -- VALU has
    // headroom; gathers above have had the whole phase to land).
    #pragma unroll
    for (int k = 0; k < EPT; ++k) {
        int m = wmask[k];
        if (m) {
            float4 en = eA[k];
            float x0f = floorf(en.x), y0f = floorf(en.y);
            int x0 = (int)x0f, y0 = (int)y0f;
            float ax = __fsub_rn(en.x, x0f);
            float ay = __fsub_rn(en.y, y0f);
            float wx[2] = { __fsub_rn(1.0f, ax), ax };
            float wy[2] = { __fsub_rn(1.0f, ay), ay };
            #pragma unroll
            for (int dy = 0; dy < 2; ++dy) {
                #pragma unroll
                for (int dx = 0; dx < 2; ++dx) {
                    if (m & (1 << (dy * 2 + dx))) {
                        int loc = ((y0 + dy - ty0) << 5) + (x0 + dx - tx0);
                        float wg = __fmul_rn(wx[dx], wy[dy]);
                        atomicAdd(&accf[4 * loc + 0], wg);
                        atomicAdd(&accf[4 * loc + 1], __fmul_rn(c0[k], wg));
                        atomicAdd(&accf[4 * loc + 2], __fmul_rn(c1[k], wg));
                        atomicAdd(&accf[4 * loc + 3], __fmul_rn(c2[k], wg));
                    }
                }
            }
        }
    }
    __syncthreads();

    float* ob = out + (size_t)b * C * HW;
    float* wb = wght + (size_t)b * HW;
    for (int i = tid; i < TPX; i += BLOCK) {
        int gy = ty0 + (i >> 5), gx = tx0 + (i & 31);
        if (gy >= H) continue;
        int g = gy * W + gx;
        float4 a = accv[i];   // ds_read_b128
        if (have_ofl) {  // overflow exists: store raw sums, norm pass finishes
            wb[g] = a.x;
            ob[g] = a.y; ob[g + HW] = a.z; ob[g + 2 * HW] = a.w;
        } else {         // common case: fused normalize
            float wv = fmaxf(a.x, 1e-5f);
            ob[g]          = __fdiv_rn(a.y, wv);
            ob[g + HW]     = __fdiv_rn(a.z, wv);
            ob[g + 2 * HW] = __fdiv_rn(a.w, wv);
        }
    }
}

// ---------------------------------------------------------------------------
// Overflow accumulation (normally zero work): global atomics, corners
// restricted to the overflowed tile (other tiles own their own copies).
__global__ __launch_bounds__(BLOCK) void k_accum_ofl(const float* __restrict__ im0,
                                                     const float2* __restrict__ flow,
                                                     const int* __restrict__ ofl_cnt,
                                                     const int* __restrict__ ofl_i,
                                                     const int* __restrict__ ofl_t,
                                                     const int* __restrict__ dbuf,
                                                     float* __restrict__ wght,
                                                     float* __restrict__ out) {
    int k = blockIdx.x * BLOCK + threadIdx.x;
    int n = min(*ofl_cnt, OFL_CAP);
    if (k >= n) return;
    int i = ofl_i[k], t = ofl_t[k];
    int b = i / HW;
    int pix = i - b * HW;
    int h = pix / W, w = pix - h * W;
    int bx = t % TXN, by = t / TXN;
    float2 f = flow[i];
    float x = (float)w + f.x;
    float y = (float)h + f.y;
    float x0f = floorf(x), y0f = floorf(y);
    int x0 = (int)x0f, y0 = (int)y0f;
    float ax = __fsub_rn(x, x0f);
    float ay = __fsub_rn(y, y0f);
    int d = depth_key(f.x, f.y);
    const float* src = im0 + (size_t)b * C * HW + pix;
    float c0 = src[0], c1 = src[HW], c2 = src[2 * HW];
    float wxv[2] = { __fsub_rn(1.0f, ax), ax };
    float wyv[2] = { __fsub_rn(1.0f, ay), ay };
    #pragma unroll
    for (int dy = 0; dy < 2; ++dy) {
        int cy = y0 + dy;
        if ((cy >> 5) != by || cy >= H) continue;
        #pragma unroll
        for (int dx = 0; dx < 2; ++dx) {
            int cx = x0 + dx;
            if ((cx >> 5) != bx) continue;
            int idx = b * HW + cy * W + cx;
            if (dbuf[idx] != d) continue;
            float wg = __fmul_rn(wxv[dx], wyv[dy]);
            atomicAdd(&wght[idx], wg);
            float* o = out + (size_t)b * C * HW + cy * W + cx;
            atomicAdd(&o[0],      __fmul_rn(c0, wg));
            atomicAdd(&o[HW],     __fmul_rn(c1, wg));
            atomicAdd(&o[2 * HW], __fmul_rn(c2, wg));
        }
    }
}

// Norm pass: only active when overflow occurred (k_tile stored raw sums).
__global__ __launch_bounds__(BLOCK) void k_norm(float* __restrict__ out,
                                                const float* __restrict__ wght,
                                                const int* __restrict__ ofl_cnt) {
    if (*ofl_cnt == 0) return;
    for (int i = blockIdx.x * BLOCK + threadIdx.x; i < NPIX;
         i += gridDim.x * BLOCK) {
        int b = i / HW;
        int pix = i - b * HW;
        float wv = fmaxf(wght[i], 1e-5f);
        float* o = out + (size_t)b * C * HW + pix;
        o[0]      = __fdiv_rn(o[0], wv);
        o[HW]     = __fdiv_rn(o[HW], wv);
        o[2 * HW] = __fdiv_rn(o[2 * HW], wv);
    }
}

extern "C" void kernel_launch(void* const* d_in, const int* in_sizes, int n_in,
                              void* d_out, int out_size, void* d_ws, size_t ws_size,
                              hipStream_t stream) {
    const float*  im0  = (const float*)d_in[0];   // [B,C,H,W]
    const float2* flow = (const float2*)d_in[1];  // [B,H,W,2] as float2
    float* out = (float*)d_out;                   // [B,C,H,W]

    // Workspace layout (bytes): bin first (16B-aligned), then scalars.
    char* ws = (char*)d_ws;
    float4* bin = (float4*)ws;                                      // B*NT*CAP*16 (~200 MB)
    const size_t bin_bytes = (size_t)B * NT * CAP * sizeof(float4);
    int*   dbuf    = (int*)(ws + bin_bytes);                        // NPIX
    float* wght    = (float*)(ws + bin_bytes + (size_t)NPIX * 4);   // NPIX
    int*   cnt     = (int*)(ws + bin_bytes + (size_t)NPIX * 8);     // B*NT
    int*   ofl_cnt = cnt + B * NT;                                  // 1 (adjacent to cnt)
    int*   ofl_i   = ofl_cnt + 1;                                   // OFL_CAP
    int*   ofl_t   = ofl_i + OFL_CAP;                               // OFL_CAP

    hipMemsetAsync(dbuf, 0, (size_t)NPIX * 4, stream);
    hipMemsetAsync(cnt, 0, (size_t)(B * NT + 1) * 4, stream);

    int bgrid = NPIX / BPIX;    // 8100
    dim3 tgrid(TXN, TYN, B);    // 60 x 34 x 4 = 8160 tiles

    k_bin      <<<bgrid, BLOCK, 0, stream>>>(flow, cnt, bin, ofl_cnt, ofl_i, ofl_t, dbuf);
    k_tile     <<<tgrid, BLOCK, 0, stream>>>(im0, cnt, bin, ofl_cnt, dbuf, wght, out);
    k_accum_ofl<<<OFL_CAP / BLOCK, BLOCK, 0, stream>>>(im0, flow, ofl_cnt, ofl_i, ofl_t, dbuf, wght, out);
    k_norm     <<<2048, BLOCK, 0, stream>>>(out, wght, ofl_cnt);
}